// Round 4
// baseline (555.072 us; speedup 1.0000x reference)
//
#include <hip/hip_runtime.h>
#include <hip/hip_bf16.h>

typedef __attribute__((ext_vector_type(8)))  short short8;
typedef __attribute__((ext_vector_type(16))) float f32x16;

#define LOG2E 1.44269504088896f
#define CS (0.125f * LOG2E)

static __device__ __forceinline__ short f2b(float f) {
  union { __hip_bfloat16 h; short s; } u; u.h = __float2bfloat16(f); return u.s;
}
static __device__ __forceinline__ f32x16 zf16() {
  f32x16 z;
#pragma unroll
  for (int i = 0; i < 16; ++i) z[i] = 0.f;
  return z;
}
static __device__ __forceinline__ f32x16 mfma32(short8 a, short8 b, f32x16 c) {
  return __builtin_amdgcn_mfma_f32_32x32x16_bf16(a, b, c, 0, 0, 0);
}

// ---------------- kernel 0: convert + transposes ----------------
__global__ void k_convert(const float* __restrict__ x, const float* __restrict__ wqkv,
                          const float* __restrict__ wout,
                          short* __restrict__ xb, short* __restrict__ wqkvT,
                          short* __restrict__ woutT) {
  const int NX = 2 * 2048 * 512;
  const int NW = 512 * 1536;
  const int NO = 512 * 512;
  int i = blockIdx.x * 256 + threadIdx.x;
  if (i < NX) {
    xb[i] = f2b(x[i]);
  } else if (i < NX + NW) {
    int o = i - NX; int n = o >> 9; int k = o & 511;
    wqkvT[o] = f2b(wqkv[k * 1536 + n]);
  } else if (i < NX + NW + NO) {
    int o = i - NX - NW; int n = o >> 9; int k = o & 511;
    woutT[o] = f2b(wout[k * 512 + n]);
  }
}

// ---------------- kernel 0b: x.sum(axis=1) into d_out ----------------
__global__ void k_xsum(const float* __restrict__ x, float* __restrict__ outacc) {
  int blk = blockIdx.x;            // 32
  int b = blk >> 4, ch = blk & 15; // 16 chunks of 128 rows
  int t = threadIdx.x;             // 256
  int f = t * 2;
  float s0 = 0.f, s1 = 0.f;
  const float* base = x + ((size_t)b * 2048 + (size_t)ch * 128) * 512;
  for (int r = 0; r < 128; ++r) {
    float2 v = *(const float2*)(base + (size_t)r * 512 + f);
    s0 += v.x; s1 += v.y;
  }
  atomicAdd(&outacc[b * 512 + f], s0);
  atomicAdd(&outacc[b * 512 + f + 1], s1);
}

// ---------------- kernel 1: qkv GEMM ----------------
__launch_bounds__(256)
__global__ void k_qkv(const short* __restrict__ xb, const short* __restrict__ wqkvT,
                      short* __restrict__ qg, short* __restrict__ kg,
                      short* __restrict__ vtmp) {
  __shared__ __align__(16) short As[128 * 64];
  __shared__ __align__(16) short Bs[128 * 64];
  int bx = blockIdx.x & 31;   // 32 M tiles
  int by = blockIdx.x >> 5;   // 12 N tiles
  int row0 = bx << 7, col0 = by << 7;
  int t = threadIdx.x, w = t >> 6, l = t & 63, li = l & 31, hi = l >> 5;
  int wr = w >> 1, wc = w & 1;
  f32x16 acc[2][2];
#pragma unroll
  for (int mi = 0; mi < 2; ++mi)
#pragma unroll
    for (int ni = 0; ni < 2; ++ni) acc[mi][ni] = zf16();

  for (int k0 = 0; k0 < 512; k0 += 64) {
    __syncthreads();
#pragma unroll
    for (int it = 0; it < 4; ++it) {
      int idx = t + it * 256;          // chunk id 0..1023
      int r = idx >> 3, pc = idx & 7;
      int4 va = *(const int4*)(xb + (size_t)(row0 + r) * 512 + k0 + pc * 8);
      int dsto = (r * 128 + pc * 16) ^ ((r & 7) << 4);
      *(int4*)((char*)As + dsto) = va;
      int4 vb = *(const int4*)(wqkvT + (size_t)(col0 + r) * 512 + k0 + pc * 8);
      *(int4*)((char*)Bs + dsto) = vb;
    }
    __syncthreads();
#pragma unroll
    for (int kk = 0; kk < 4; ++kk) {
      short8 af[2], bfv[2];
#pragma unroll
      for (int mi = 0; mi < 2; ++mi) {
        int row = wr * 64 + mi * 32 + li;
        int byteo = (row * 128 + (kk * 2 + hi) * 16) ^ ((row & 7) << 4);
        af[mi] = *(const short8*)((char*)As + byteo);
      }
#pragma unroll
      for (int ni = 0; ni < 2; ++ni) {
        int col = wc * 64 + ni * 32 + li;
        int byteo = (col * 128 + (kk * 2 + hi) * 16) ^ ((col & 7) << 4);
        bfv[ni] = *(const short8*)((char*)Bs + byteo);
      }
#pragma unroll
      for (int mi = 0; mi < 2; ++mi)
#pragma unroll
        for (int ni = 0; ni < 2; ++ni)
          acc[mi][ni] = mfma32(af[mi], bfv[ni], acc[mi][ni]);
    }
  }
  // epilogue scatter
#pragma unroll
  for (int mi = 0; mi < 2; ++mi)
#pragma unroll
    for (int ni = 0; ni < 2; ++ni) {
      int colb = col0 + wc * 64 + ni * 32 + li;
      int sect = colb >> 9, rem = colb & 511, h = rem >> 6, d = rem & 63;
      short* dst = sect == 0 ? qg : (sect == 1 ? kg : vtmp);
#pragma unroll
      for (int r = 0; r < 16; ++r) {
        int row = row0 + wr * 64 + mi * 32 + ((r & 3) + ((r >> 2) << 3) + (hi << 2));
        int b = row >> 11, nn = row & 2047;
        dst[(((size_t)(b * 8 + h) * 2048 + nn) << 6) + d] = f2b(acc[mi][ni][r]);
      }
    }
}

// ---------------- kernel 1b: transpose v -> vt[b][h][d][n] ----------------
__global__ void k_vt(const short* __restrict__ vtmp, short* __restrict__ vt) {
  __shared__ __align__(16) short tile[64 * 72];
  int blk = blockIdx.x;        // 512
  int bh = blk >> 5;           // 0..15
  int n0 = (blk & 31) << 6;
  int t = threadIdx.x;         // 256
#pragma unroll
  for (int it = 0; it < 2; ++it) {
    int idx = (t + it * 256) * 8;
    int r = idx >> 6, c = idx & 63;
    int4 v = *(const int4*)(vtmp + ((size_t)bh * 2048 + n0 + r) * 64 + c);
    *(int4*)(&tile[r * 72 + c]) = v;
  }
  __syncthreads();
#pragma unroll
  for (int it = 0; it < 2; ++it) {
    int idx = (t + it * 256) * 8;
    int d = idx >> 6, nn = idx & 63;
    short8 o;
#pragma unroll
    for (int j = 0; j < 8; ++j) o[j] = tile[(nn + j) * 72 + d];
    *(short8*)(vt + ((size_t)bh * 64 + d) * 2048 + n0 + nn) = o;
  }
}

// ---------------- kernel 2a: softmax stats (m in log2 domain, l) ----------------
__launch_bounds__(256)
__global__ void k_stats(const short* __restrict__ qg, const short* __restrict__ kg,
                        float* __restrict__ ml) {
  int w = threadIdx.x >> 6, l = threadIdx.x & 63, li = l & 31, hi = l >> 5;
  int wt = blockIdx.x * 4 + w;           // 1024 wave tasks
  int b = wt >> 9, rem = wt & 511, h = rem >> 6, it = rem & 63;
  size_t bh = (size_t)(b * 8 + h) * 2048;
  int i = it * 32 + li;
  short8 q4[4];
#pragma unroll
  for (int kk = 0; kk < 4; ++kk)
    q4[kk] = *(const short8*)(qg + (bh + i) * 64 + kk * 16 + hi * 8);
  float m2 = -1e30f, ls = 0.f;
  for (int jt = 0; jt < 64; ++jt) {
    f32x16 s = zf16();
#pragma unroll
    for (int kk = 0; kk < 4; ++kk) {
      short8 kf = *(const short8*)(kg + (bh + jt * 32 + li) * 64 + kk * 16 + hi * 8);
      s = mfma32(kf, q4[kk], s);
    }
    float sv[16];
    float tm = -1e30f;
#pragma unroll
    for (int r = 0; r < 16; ++r) { sv[r] = s[r] * CS; tm = fmaxf(tm, sv[r]); }
    float mn = fmaxf(m2, tm);
    float acc = 0.f;
#pragma unroll
    for (int r = 0; r < 16; ++r) acc += exp2f(sv[r] - mn);
    ls = ls * exp2f(m2 - mn) + acc;
    m2 = mn;
  }
  float om = __shfl_xor(m2, 32, 64);
  float ol = __shfl_xor(ls, 32, 64);
  float mf = fmaxf(m2, om);
  float lf = ls * exp2f(m2 - mf) + ol * exp2f(om - mf);
  if (hi == 0) {
    float2 v = make_float2(mf, lf);
    *(float2*)(ml + (bh + i) * 2) = v;
  }
}

// ---------------- kernel 2b: fused attn (p, mix, LN, write attn, PV) ----------------
__launch_bounds__(512)
__global__ void k_attn(const short* __restrict__ qg, const short* __restrict__ kg,
                       const short* __restrict__ vt, const float* __restrict__ ml,
                       const float* __restrict__ mixg, const float* __restrict__ lnhg,
                       const float* __restrict__ lnhb, float* __restrict__ attn,
                       float* __restrict__ oh) {
  __shared__ __align__(16) float p_lds[8 * 32 * 33];
  __shared__ __align__(16) short a_lds[8 * 32 * 40];
  int t = threadIdx.x;
  int w = t >> 6, l = t & 63, li = l & 31, hi = l >> 5;
  int blk = blockIdx.x;           // 512
  int jg = blk & 3, itile = (blk >> 2) & 63, b = blk >> 8;
  int i0 = itile * 32;
  int h = w;
  size_t bh = (size_t)(b * 8 + h) * 2048;

  float mixr[64];
#pragma unroll
  for (int z = 0; z < 64; ++z) mixr[z] = mixg[z];
  float lg[8], lbv[8];
#pragma unroll
  for (int g = 0; g < 8; ++g) { lg[g] = lnhg[g]; lbv[g] = lnhb[g]; }

  short8 q4[4];
#pragma unroll
  for (int kk = 0; kk < 4; ++kk)
    q4[kk] = *(const short8*)(qg + (bh + i0 + li) * 64 + kk * 16 + hi * 8);
  float2 mlv = *(const float2*)(ml + (bh + i0 + li) * 2);
  float mI = mlv.x;
  float rl = 1.0f / mlv.y;

  f32x16 oacc[2];
  oacc[0] = zf16(); oacc[1] = zf16();

  int jj = t & 31;
  int ipb = (t >> 5) & 15;

  for (int jt = 0; jt < 16; ++jt) {
    int j0 = jg * 512 + jt * 32;
    f32x16 s = zf16();
#pragma unroll
    for (int kk = 0; kk < 4; ++kk) {
      short8 kf = *(const short8*)(kg + (bh + j0 + li) * 64 + kk * 16 + hi * 8);
      s = mfma32(kf, q4[kk], s);
    }
#pragma unroll
    for (int r = 0; r < 16; ++r) {
      float p = exp2f(fmaf(s[r], CS, -mI)) * rl;
      int jr = (r & 3) + ((r >> 2) << 3) + (hi << 2);
      p_lds[(h * 32 + jr) * 33 + li] = p;
    }
    __syncthreads();
#pragma unroll
    for (int pp = 0; pp < 2; ++pp) {
      int ip = ipb + pp * 16;
      float ph[8];
#pragma unroll
      for (int g = 0; g < 8; ++g) ph[g] = p_lds[(g * 32 + jj) * 33 + ip];
      float a[8];
#pragma unroll
      for (int g = 0; g < 8; ++g) {
        float a2 = 0.f;
#pragma unroll
        for (int hh = 0; hh < 8; ++hh) a2 = fmaf(ph[hh], mixr[hh * 8 + g], a2);
        a[g] = a2;
      }
      float mu = 0.f;
#pragma unroll
      for (int g = 0; g < 8; ++g) mu += a[g];
      mu *= 0.125f;
      float var = 0.f;
#pragma unroll
      for (int g = 0; g < 8; ++g) { float d2 = a[g] - mu; var = fmaf(d2, d2, var); }
      var *= 0.125f;
      float rs = rsqrtf(var + 1e-5f);
#pragma unroll
      for (int g = 0; g < 8; ++g) {
        float y = (a[g] - mu) * rs * lg[g] + lbv[g];
        attn[((size_t)(b * 8 + g) * 2048 + (size_t)(i0 + ip)) * 2048 + j0 + jj] = y;
        a_lds[(g * 32 + ip) * 40 + jj] = f2b(y);
      }
    }
    __syncthreads();
#pragma unroll
    for (int ks = 0; ks < 2; ++ks) {
      short8 af = *(const short8*)(&a_lds[(h * 32 + li) * 40 + ks * 16 + hi * 8]);
#pragma unroll
      for (int dt = 0; dt < 2; ++dt) {
        short8 vf = *(const short8*)(vt + ((size_t)(b * 8 + h) * 64 + dt * 32 + li) * 2048 + j0 + ks * 16 + hi * 8);
        oacc[dt] = mfma32(af, vf, oacc[dt]);
      }
    }
  }
  // oh layout: [b][n][h*64+d]  (matches k_epi's A-matrix view)
#pragma unroll
  for (int dt = 0; dt < 2; ++dt)
#pragma unroll
    for (int r = 0; r < 16; ++r) {
      int ri = (r & 3) + ((r >> 2) << 3) + (hi << 2);
      atomicAdd(&oh[((size_t)(b * 2048 + i0 + ri)) * 512 + h * 64 + dt * 32 + li], oacc[dt][r]);
    }
}

// ---------------- kernel 3: epilogue GEMM + LN + reduce ----------------
__launch_bounds__(512)
__global__ void k_epi(const float* __restrict__ oh, const short* __restrict__ woutT,
                      const float* __restrict__ bo, const float* __restrict__ logv,
                      const float* __restrict__ lob, float* __restrict__ dout) {
  __shared__ __align__(16) short As[64 * 64];
  __shared__ float lnsum[64][4];
  __shared__ float lnsq[64][4];
  __shared__ float zsum[512];
  int t = threadIdx.x, w = t >> 6, l = t & 63, li = l & 31, hi = l >> 5;
  int rb = w >> 2, cb = w & 3;
  int m0 = blockIdx.x * 64;         // 64 blocks
  zsum[t] = 0.f;
  f32x16 acc[4];
#pragma unroll
  for (int ni = 0; ni < 4; ++ni) acc[ni] = zf16();

  for (int k0 = 0; k0 < 512; k0 += 64) {
    __syncthreads();
    {
      int r = t >> 3, c = (t & 7) * 8;
      float4 v0 = *(const float4*)(oh + (size_t)(m0 + r) * 512 + k0 + c);
      float4 v1 = *(const float4*)(oh + (size_t)(m0 + r) * 512 + k0 + c + 4);
      short8 o;
      o[0] = f2b(v0.x); o[1] = f2b(v0.y); o[2] = f2b(v0.z); o[3] = f2b(v0.w);
      o[4] = f2b(v1.x); o[5] = f2b(v1.y); o[6] = f2b(v1.z); o[7] = f2b(v1.w);
      int byteo = (r * 128 + c * 2) ^ ((r & 7) << 4);
      *(short8*)((char*)As + byteo) = o;
    }
    __syncthreads();
#pragma unroll
    for (int kk = 0; kk < 4; ++kk) {
      int rowA = rb * 32 + li;
      int byteo = (rowA * 128 + (kk * 2 + hi) * 16) ^ ((rowA & 7) << 4);
      short8 af = *(const short8*)((char*)As + byteo);
#pragma unroll
      for (int ni = 0; ni < 4; ++ni) {
        int n = cb * 128 + ni * 32 + li;
        short8 bfr = *(const short8*)(woutT + (size_t)n * 512 + k0 + kk * 16 + hi * 8);
        acc[ni] = mfma32(af, bfr, acc[ni]);
      }
    }
  }
  float bias[4], gg[4], b2[4];
#pragma unroll
  for (int ni = 0; ni < 4; ++ni) {
    int n = cb * 128 + ni * 32 + li;
    bias[ni] = bo[n]; gg[ni] = logv[n]; b2[ni] = lob[n];
  }
#pragma unroll
  for (int ni = 0; ni < 4; ++ni)
#pragma unroll
    for (int r = 0; r < 16; ++r) acc[ni][r] += bias[ni];

#pragma unroll
  for (int r = 0; r < 16; ++r) {
    float s = 0.f, q2 = 0.f;
#pragma unroll
    for (int ni = 0; ni < 4; ++ni) { float v = acc[ni][r]; s += v; q2 = fmaf(v, v, q2); }
    for (int d2 = 1; d2 < 32; d2 <<= 1) { s += __shfl_xor(s, d2); q2 += __shfl_xor(q2, d2); }
    int rw = rb * 32 + (r & 3) + ((r >> 2) << 3) + (hi << 2);
    if (li == 0) { lnsum[rw][cb] = s; lnsq[rw][cb] = q2; }
  }
  __syncthreads();
  float zp[4] = {0.f, 0.f, 0.f, 0.f};
#pragma unroll
  for (int r = 0; r < 16; ++r) {
    int rw = rb * 32 + (r & 3) + ((r >> 2) << 3) + (hi << 2);
    float s = lnsum[rw][0] + lnsum[rw][1] + lnsum[rw][2] + lnsum[rw][3];
    float q2 = lnsq[rw][0] + lnsq[rw][1] + lnsq[rw][2] + lnsq[rw][3];
    float mu = s * (1.f / 512.f);
    float var = q2 * (1.f / 512.f) - mu * mu;
    float rs = rsqrtf(var + 1e-5f);
#pragma unroll
    for (int ni = 0; ni < 4; ++ni) {
      float y = (acc[ni][r] - mu) * rs * gg[ni] + b2[ni];
      zp[ni] += y;
    }
  }
#pragma unroll
  for (int ni = 0; ni < 4; ++ni) zp[ni] += __shfl_xor(zp[ni], 32);
  if (hi == 0) {
#pragma unroll
    for (int ni = 0; ni < 4; ++ni) atomicAdd(&zsum[cb * 128 + ni * 32 + li], zp[ni]);
  }
  __syncthreads();
  int bsel = m0 >> 11;
  atomicAdd(&dout[bsel * 512 + t], zsum[t]);
}

// ---------------- launch ----------------
extern "C" void kernel_launch(void* const* d_in, const int* in_sizes, int n_in,
                              void* d_out, int out_size, void* d_ws, size_t ws_size,
                              hipStream_t stream) {
  const float* x    = (const float*)d_in[0];
  const float* wqkv = (const float*)d_in[1];
  const float* mixg = (const float*)d_in[2];
  const float* lnhg = (const float*)d_in[3];
  const float* lnhb = (const float*)d_in[4];
  const float* wout = (const float*)d_in[5];
  const float* bo   = (const float*)d_in[6];
  const float* logv = (const float*)d_in[7];
  const float* lob  = (const float*)d_in[8];
  float* dout = (float*)d_out;
  char* ws = (char*)d_ws;
  short* xb    = (short*)(ws + 0);
  short* wqkvT = (short*)(ws + 4194304);
  short* woutT = (short*)(ws + 5767168);
  short* qg    = (short*)(ws + 6291456);
  short* kg    = (short*)(ws + 10485760);
  short* vtmp  = (short*)(ws + 14680064);
  short* vt    = (short*)(ws + 18874368);
  float* ml    = (float*)(ws + 23068672);
  float* oh    = (float*)(ws + 23330816);

  hipMemsetAsync(dout, 0, 1024 * sizeof(float), stream);
  hipMemsetAsync(oh, 0, (size_t)2 * 2048 * 512 * 4, stream);

  k_convert<<<12288, 256, 0, stream>>>(x, wqkv, wout, xb, wqkvT, woutT);
  k_xsum<<<32, 256, 0, stream>>>(x, dout);
  k_qkv<<<384, 256, 0, stream>>>(xb, wqkvT, qg, kg, vtmp);
  k_vt<<<512, 256, 0, stream>>>(vtmp, vt);
  k_stats<<<256, 256, 0, stream>>>(qg, kg, ml);
  k_attn<<<512, 512, 0, stream>>>(qg, kg, vt, ml, mixg, lnhg, lnhb, dout + 1024, oh);
  k_epi<<<64, 512, 0, stream>>>(oh, woutT, bo, logv, lob, dout);
}

// Round 6
// 452.403 us; speedup vs baseline: 1.2269x; 1.2269x over previous
//
#include <hip/hip_runtime.h>
#include <hip/hip_bf16.h>

typedef __attribute__((ext_vector_type(8)))  short short8;
typedef __attribute__((ext_vector_type(16))) float f32x16;

#define LOG2E 1.44269504088896f
#define CS (0.125f * LOG2E)

static __device__ __forceinline__ short f2b(float f) {
  union { __hip_bfloat16 h; short s; } u; u.h = __float2bfloat16(f); return u.s;
}
static __device__ __forceinline__ f32x16 zf16() {
  f32x16 z;
#pragma unroll
  for (int i = 0; i < 16; ++i) z[i] = 0.f;
  return z;
}
static __device__ __forceinline__ f32x16 mfma32(short8 a, short8 b, f32x16 c) {
  return __builtin_amdgcn_mfma_f32_32x32x16_bf16(a, b, c, 0, 0, 0);
}
static __device__ __forceinline__ float rfl(float v) {
  return __int_as_float(__builtin_amdgcn_readfirstlane(__float_as_int(v)));
}

// ---------------- kernel 0: convert + transposes ----------------
__global__ void k_convert(const float* __restrict__ x, const float* __restrict__ wqkv,
                          const float* __restrict__ wout,
                          short* __restrict__ xb, short* __restrict__ wqkvT,
                          short* __restrict__ woutT) {
  const int NX = 2 * 2048 * 512;
  const int NW = 512 * 1536;
  const int NO = 512 * 512;
  int i = blockIdx.x * 256 + threadIdx.x;
  if (i < NX) {
    xb[i] = f2b(x[i]);
  } else if (i < NX + NW) {
    int o = i - NX; int n = o >> 9; int k = o & 511;
    wqkvT[o] = f2b(wqkv[k * 1536 + n]);
  } else if (i < NX + NW + NO) {
    int o = i - NX - NW; int n = o >> 9; int k = o & 511;
    woutT[o] = f2b(wout[k * 512 + n]);
  }
}

// ---------------- kernel 0b: x.sum(axis=1) into d_out ----------------
__global__ void k_xsum(const float* __restrict__ x, float* __restrict__ outacc) {
  int blk = blockIdx.x;            // 32
  int b = blk >> 4, ch = blk & 15;
  int t = threadIdx.x;             // 256
  int f = t * 2;
  float s0 = 0.f, s1 = 0.f;
  const float* base = x + ((size_t)b * 2048 + (size_t)ch * 128) * 512;
  for (int r = 0; r < 128; ++r) {
    float2 v = *(const float2*)(base + (size_t)r * 512 + f);
    s0 += v.x; s1 += v.y;
  }
  atomicAdd(&outacc[b * 512 + f], s0);
  atomicAdd(&outacc[b * 512 + f + 1], s1);
}

// ---------------- kernel 1: qkv GEMM ----------------
__launch_bounds__(256)
__global__ void k_qkv(const short* __restrict__ xb, const short* __restrict__ wqkvT,
                      short* __restrict__ qg, short* __restrict__ kg,
                      short* __restrict__ vtmp) {
  __shared__ __align__(16) short As[128 * 64];
  __shared__ __align__(16) short Bs[128 * 64];
  int bx = blockIdx.x & 31;
  int by = blockIdx.x >> 5;
  int row0 = bx << 7, col0 = by << 7;
  int t = threadIdx.x, w = t >> 6, l = t & 63, li = l & 31, hi = l >> 5;
  int wr = w >> 1, wc = w & 1;
  f32x16 acc[2][2];
#pragma unroll
  for (int mi = 0; mi < 2; ++mi)
#pragma unroll
    for (int ni = 0; ni < 2; ++ni) acc[mi][ni] = zf16();

  for (int k0 = 0; k0 < 512; k0 += 64) {
    __syncthreads();
#pragma unroll
    for (int it = 0; it < 4; ++it) {
      int idx = t + it * 256;
      int r = idx >> 3, pc = idx & 7;
      int4 va = *(const int4*)(xb + (size_t)(row0 + r) * 512 + k0 + pc * 8);
      int dsto = (r * 128 + pc * 16) ^ ((r & 7) << 4);
      *(int4*)((char*)As + dsto) = va;
      int4 vb = *(const int4*)(wqkvT + (size_t)(col0 + r) * 512 + k0 + pc * 8);
      *(int4*)((char*)Bs + dsto) = vb;
    }
    __syncthreads();
#pragma unroll
    for (int kk = 0; kk < 4; ++kk) {
      short8 af[2], bfv[2];
#pragma unroll
      for (int mi = 0; mi < 2; ++mi) {
        int row = wr * 64 + mi * 32 + li;
        int byteo = (row * 128 + (kk * 2 + hi) * 16) ^ ((row & 7) << 4);
        af[mi] = *(const short8*)((char*)As + byteo);
      }
#pragma unroll
      for (int ni = 0; ni < 2; ++ni) {
        int col = wc * 64 + ni * 32 + li;
        int byteo = (col * 128 + (kk * 2 + hi) * 16) ^ ((col & 7) << 4);
        bfv[ni] = *(const short8*)((char*)Bs + byteo);
      }
#pragma unroll
      for (int mi = 0; mi < 2; ++mi)
#pragma unroll
        for (int ni = 0; ni < 2; ++ni)
          acc[mi][ni] = mfma32(af[mi], bfv[ni], acc[mi][ni]);
    }
  }
#pragma unroll
  for (int mi = 0; mi < 2; ++mi)
#pragma unroll
    for (int ni = 0; ni < 2; ++ni) {
      int colb = col0 + wc * 64 + ni * 32 + li;
      int sect = colb >> 9, rem = colb & 511, h = rem >> 6, d = rem & 63;
      short* dst = sect == 0 ? qg : (sect == 1 ? kg : vtmp);
#pragma unroll
      for (int r = 0; r < 16; ++r) {
        int row = row0 + wr * 64 + mi * 32 + ((r & 3) + ((r >> 2) << 3) + (hi << 2));
        int b = row >> 11, nn = row & 2047;
        dst[(((size_t)(b * 8 + h) * 2048 + nn) << 6) + d] = f2b(acc[mi][ni][r]);
      }
    }
}

// ---------------- kernel 1b: transpose v -> vt[b][h][d][n] ----------------
__global__ void k_vt(const short* __restrict__ vtmp, short* __restrict__ vt) {
  __shared__ __align__(16) short tile[64 * 72];
  int blk = blockIdx.x;        // 512
  int bh = blk >> 5;
  int n0 = (blk & 31) << 6;
  int t = threadIdx.x;         // 256
#pragma unroll
  for (int it = 0; it < 2; ++it) {
    int idx = (t + it * 256) * 8;
    int r = idx >> 6, c = idx & 63;
    int4 v = *(const int4*)(vtmp + ((size_t)bh * 2048 + n0 + r) * 64 + c);
    *(int4*)(&tile[r * 72 + c]) = v;
  }
  __syncthreads();
#pragma unroll
  for (int it = 0; it < 2; ++it) {
    int idx = (t + it * 256) * 8;
    int d = idx >> 6, nn = idx & 63;
    short8 o;
#pragma unroll
    for (int j = 0; j < 8; ++j) o[j] = tile[(nn + j) * 72 + d];
    *(short8*)(vt + ((size_t)bh * 64 + d) * 2048 + n0 + nn) = o;
  }
}

// ---------------- kernel 2a: softmax stats, 4-wave j-split ----------------
__launch_bounds__(256)
__global__ void k_stats(const short* __restrict__ qg, const short* __restrict__ kg,
                        float* __restrict__ ml) {
  __shared__ float red[4][32][2];
  int t = threadIdx.x, w = t >> 6, l = t & 63, li = l & 31, hi = l >> 5;
  int blk = blockIdx.x;                  // 1024 = b*h*it
  int b = blk >> 9, rem = blk & 511, h = rem >> 6, it = rem & 63;
  size_t bh = (size_t)(b * 8 + h) * 2048;
  int i = it * 32 + li;
  short8 q4[4];
#pragma unroll
  for (int kk = 0; kk < 4; ++kk)
    q4[kk] = *(const short8*)(qg + (bh + i) * 64 + kk * 16 + hi * 8);
  float m2 = -1e30f, ls = 0.f;
  for (int jt = w * 16; jt < w * 16 + 16; ++jt) {
    f32x16 s = zf16();
#pragma unroll
    for (int kk = 0; kk < 4; ++kk) {
      short8 kf = *(const short8*)(kg + (bh + jt * 32 + li) * 64 + kk * 16 + hi * 8);
      s = mfma32(kf, q4[kk], s);
    }
    float sv[16];
    float tm = -1e30f;
#pragma unroll
    for (int r = 0; r < 16; ++r) { sv[r] = s[r] * CS; tm = fmaxf(tm, sv[r]); }
    float mn = fmaxf(m2, tm);
    float acc = 0.f;
#pragma unroll
    for (int r = 0; r < 16; ++r) acc += exp2f(sv[r] - mn);
    ls = ls * exp2f(m2 - mn) + acc;
    m2 = mn;
  }
  // merge hi halves within wave
  float om = __shfl_xor(m2, 32, 64);
  float ol = __shfl_xor(ls, 32, 64);
  float mf = fmaxf(m2, om);
  float lf = ls * exp2f(m2 - mf) + ol * exp2f(om - mf);
  if (hi == 0) { red[w][li][0] = mf; red[w][li][1] = lf; }
  __syncthreads();
  if (t < 32) {
    float m = red[0][t][0], s = red[0][t][1];
#pragma unroll
    for (int ww = 1; ww < 4; ++ww) {
      float m1 = red[ww][t][0], s1 = red[ww][t][1];
      float mn = fmaxf(m, m1);
      s = s * exp2f(m - mn) + s1 * exp2f(m1 - mn);
      m = mn;
    }
    *(float2*)(ml + (bh + it * 32 + t) * 2) = make_float2(m, s);
  }
}

// ---------------- kernel 2b: fused attn ----------------
__launch_bounds__(512, 4)
__global__ void k_attn(const short* __restrict__ qg, const short* __restrict__ kg,
                       const short* __restrict__ vt, const float* __restrict__ ml,
                       const float* __restrict__ mixg, const float* __restrict__ lnhg,
                       const float* __restrict__ lnhb, float* __restrict__ attn,
                       float* __restrict__ oh) {
  __shared__ __align__(16) float p_lds[8 * 32 * 33];
  __shared__ __align__(16) short a_lds[8 * 32 * 40];
  int t = threadIdx.x;
  int w = t >> 6, l = t & 63, li = l & 31, hi = l >> 5;
  int blk = blockIdx.x;           // 512
  int jg = blk & 3, itile = (blk >> 2) & 63, b = blk >> 8;
  int i0 = itile * 32;
  int h = w;
  size_t bh = (size_t)(b * 8 + h) * 2048;

  // SGPR-resident coefficients (wave-uniform; VOP3 FMA reads 1 SGPR operand)
  float mixr[64];
#pragma unroll
  for (int z = 0; z < 64; ++z) mixr[z] = rfl(mixg[z]);
  float lg[8], lbv[8];
#pragma unroll
  for (int g = 0; g < 8; ++g) { lg[g] = rfl(lnhg[g]); lbv[g] = rfl(lnhb[g]); }

  short8 q4[4];
#pragma unroll
  for (int kk = 0; kk < 4; ++kk)
    q4[kk] = *(const short8*)(qg + (bh + i0 + li) * 64 + kk * 16 + hi * 8);
  float2 mlv = *(const float2*)(ml + (bh + i0 + li) * 2);
  float c0 = -(mlv.x + __log2f(mlv.y));   // p = exp2(s*CS + c0)

  f32x16 oacc[2];
  oacc[0] = zf16(); oacc[1] = zf16();

  int ii = t >> 4;            // mix-phase q-row 0..31
  int jp = (t & 15) * 2;      // mix-phase j pair (even)

  for (int jt = 0; jt < 16; ++jt) {
    int j0 = jg * 512 + jt * 32;
    f32x16 s = zf16();
#pragma unroll
    for (int kk = 0; kk < 4; ++kk) {
      short8 kf = *(const short8*)(kg + (bh + j0 + li) * 64 + kk * 16 + hi * 8);
      s = mfma32(kf, q4[kk], s);
    }
#pragma unroll
    for (int r = 0; r < 16; ++r) {
      float p = exp2f(fmaf(s[r], CS, c0));
      int jr = (r & 3) + ((r >> 2) << 3) + (hi << 2);
      p_lds[(h * 32 + jr) * 33 + li] = p;
    }
    __syncthreads();
    // ---- mix + head-LN for 2 consecutive j columns ----
    {
      float pf[8][2], a[8][2];
#pragma unroll
      for (int g = 0; g < 8; ++g) {
        pf[g][0] = p_lds[(g * 32 + jp) * 33 + ii];
        pf[g][1] = p_lds[(g * 32 + jp + 1) * 33 + ii];
      }
#pragma unroll
      for (int g = 0; g < 8; ++g) {
#pragma unroll
        for (int jb = 0; jb < 2; ++jb) {
          float a2 = 0.f;
#pragma unroll
          for (int hh = 0; hh < 8; ++hh) a2 = fmaf(pf[hh][jb], mixr[hh * 8 + g], a2);
          a[g][jb] = a2;
        }
      }
      float mu[2], rs[2];
#pragma unroll
      for (int jb = 0; jb < 2; ++jb) {
        float m2 = 0.f;
#pragma unroll
        for (int g = 0; g < 8; ++g) m2 += a[g][jb];
        m2 *= 0.125f;
        float var = 0.f;
#pragma unroll
        for (int g = 0; g < 8; ++g) { float d2 = a[g][jb] - m2; var = fmaf(d2, d2, var); }
        var *= 0.125f;
        mu[jb] = m2; rs[jb] = rsqrtf(var + 1e-5f);
      }
#pragma unroll
      for (int g = 0; g < 8; ++g) {
        float y0 = (a[g][0] - mu[0]) * rs[0] * lg[g] + lbv[g];
        float y1 = (a[g][1] - mu[1]) * rs[1] * lg[g] + lbv[g];
        *(float2*)(&attn[((size_t)(b * 8 + g) * 2048 + (size_t)(i0 + ii)) * 2048 + j0 + jp]) =
            make_float2(y0, y1);
        unsigned int pk = (unsigned short)f2b(y0) | ((unsigned int)(unsigned short)f2b(y1) << 16);
        *(unsigned int*)(&a_lds[(g * 32 + ii) * 40 + jp]) = pk;
      }
    }
    __syncthreads();
#pragma unroll
    for (int ks = 0; ks < 2; ++ks) {
      short8 af = *(const short8*)(&a_lds[(h * 32 + li) * 40 + ks * 16 + hi * 8]);
#pragma unroll
      for (int dt = 0; dt < 2; ++dt) {
        short8 vf = *(const short8*)(vt + ((size_t)(b * 8 + h) * 64 + dt * 32 + li) * 2048 + j0 + ks * 16 + hi * 8);
        oacc[dt] = mfma32(af, vf, oacc[dt]);
      }
    }
  }
  // partial oh per jg (no atomics); layout [jg][b][n][h*64+d]
  float* ohp = oh + (size_t)jg * (2 * 2048 * 512);
#pragma unroll
  for (int dt = 0; dt < 2; ++dt)
#pragma unroll
    for (int r = 0; r < 16; ++r) {
      int ri = (r & 3) + ((r >> 2) << 3) + (hi << 2);
      ohp[((size_t)(b * 2048 + i0 + ri)) * 512 + h * 64 + dt * 32 + li] = oacc[dt][r];
    }
}

// ---------------- kernel 3: epilogue GEMM + LN + reduce (32-row tiles) ----------------
__launch_bounds__(512)
__global__ void k_epi(const float* __restrict__ oh, const short* __restrict__ woutT,
                      const float* __restrict__ bo, const float* __restrict__ logv,
                      const float* __restrict__ lob, float* __restrict__ dout) {
  __shared__ __align__(16) short As[32 * 64];
  __shared__ float lnsum[32][8];
  __shared__ float lnsq[32][8];
  __shared__ float zsum[512];
  const size_t NPART = (size_t)2 * 2048 * 512;
  int t = threadIdx.x, w = t >> 6, l = t & 63, li = l & 31, hi = l >> 5;
  int m0 = blockIdx.x * 32;         // 128 blocks
  f32x16 acc[2];
  acc[0] = zf16(); acc[1] = zf16();

  for (int k0 = 0; k0 < 512; k0 += 64) {
    __syncthreads();
    {
      int r = t >> 4, c = (t & 15) * 4;
      size_t off = (size_t)(m0 + r) * 512 + k0 + c;
      float4 v = *(const float4*)(oh + off);
#pragma unroll
      for (int p = 1; p < 4; ++p) {
        float4 v2 = *(const float4*)(oh + p * NPART + off);
        v.x += v2.x; v.y += v2.y; v.z += v2.z; v.w += v2.w;
      }
      short o[4] = { f2b(v.x), f2b(v.y), f2b(v.z), f2b(v.w) };
      int byteo = (r * 128 + c * 2) ^ ((r & 7) << 4);
      *(int2*)((char*)As + byteo) = *(int2*)o;
    }
    __syncthreads();
#pragma unroll
    for (int kk = 0; kk < 4; ++kk) {
      int byteo = (li * 128 + (kk * 2 + hi) * 16) ^ ((li & 7) << 4);
      short8 af = *(const short8*)((char*)As + byteo);
#pragma unroll
      for (int ni = 0; ni < 2; ++ni) {
        int n = w * 64 + ni * 32 + li;
        short8 bfr = *(const short8*)(woutT + (size_t)n * 512 + k0 + kk * 16 + hi * 8);
        acc[ni] = mfma32(af, bfr, acc[ni]);
      }
    }
  }
  float bias[2], gg[2], b2[2];
#pragma unroll
  for (int ni = 0; ni < 2; ++ni) {
    int n = w * 64 + ni * 32 + li;
    bias[ni] = bo[n]; gg[ni] = logv[n]; b2[ni] = lob[n];
  }
#pragma unroll
  for (int ni = 0; ni < 2; ++ni)
#pragma unroll
    for (int r = 0; r < 16; ++r) acc[ni][r] += bias[ni];

  // per-row sums (rows 0..31 within tile)
#pragma unroll
  for (int r = 0; r < 16; ++r) {
    float s = acc[0][r] + acc[1][r];
    float q2 = fmaf(acc[0][r], acc[0][r], acc[1][r] * acc[1][r]);
    for (int d2 = 1; d2 < 32; d2 <<= 1) { s += __shfl_xor(s, d2); q2 += __shfl_xor(q2, d2); }
    int row = (r & 3) + ((r >> 2) << 3) + (hi << 2);
    if (li == 0) { lnsum[row][w] = s; lnsq[row][w] = q2; }
  }
  __syncthreads();
  if (t < 32) {
    float s = 0.f, q2 = 0.f;
#pragma unroll
    for (int ww = 0; ww < 8; ++ww) { s += lnsum[t][ww]; q2 += lnsq[t][ww]; }
    float m2 = s * (1.f / 512.f);
    float var = q2 * (1.f / 512.f) - m2 * m2;
    lnsum[t][0] = m2;
    lnsq[t][0] = rsqrtf(var + 1e-5f);
  }
  __syncthreads();
  float zc[2] = {0.f, 0.f};
#pragma unroll
  for (int r = 0; r < 16; ++r) {
    int row = (r & 3) + ((r >> 2) << 3) + (hi << 2);
    float m2 = lnsum[row][0], rs = lnsq[row][0];
#pragma unroll
    for (int ni = 0; ni < 2; ++ni)
      zc[ni] += (acc[ni][r] - m2) * rs * gg[ni] + b2[ni];
  }
#pragma unroll
  for (int ni = 0; ni < 2; ++ni) zc[ni] += __shfl_xor(zc[ni], 32);
  if (hi == 0) {
#pragma unroll
    for (int ni = 0; ni < 2; ++ni) zsum[w * 64 + ni * 32 + li] = zc[ni];
  }
  __syncthreads();
  int bsel = m0 >> 11;
  atomicAdd(&dout[bsel * 512 + t], zsum[t]);
}

// ---------------- launch ----------------
extern "C" void kernel_launch(void* const* d_in, const int* in_sizes, int n_in,
                              void* d_out, int out_size, void* d_ws, size_t ws_size,
                              hipStream_t stream) {
  const float* x    = (const float*)d_in[0];
  const float* wqkv = (const float*)d_in[1];
  const float* mixg = (const float*)d_in[2];
  const float* lnhg = (const float*)d_in[3];
  const float* lnhb = (const float*)d_in[4];
  const float* wout = (const float*)d_in[5];
  const float* bo   = (const float*)d_in[6];
  const float* logv = (const float*)d_in[7];
  const float* lob  = (const float*)d_in[8];
  float* dout = (float*)d_out;
  char* ws = (char*)d_ws;
  short* xb    = (short*)(ws + 0);
  short* wqkvT = (short*)(ws + 4194304);
  short* woutT = (short*)(ws + 5767168);
  short* qg    = (short*)(ws + 6291456);
  short* kg    = (short*)(ws + 10485760);
  short* vtmp  = (short*)(ws + 14680064);
  short* vt    = (short*)(ws + 18874368);
  float* ml    = (float*)(ws + 23068672);
  float* oh    = (float*)(ws + 23330816);   // 4 partials × 8 MB

  hipMemsetAsync(dout, 0, 1024 * sizeof(float), stream);

  k_convert<<<12288, 256, 0, stream>>>(x, wqkv, wout, xb, wqkvT, woutT);
  k_xsum<<<32, 256, 0, stream>>>(x, dout);
  k_qkv<<<384, 256, 0, stream>>>(xb, wqkvT, qg, kg, vtmp);
  k_vt<<<512, 256, 0, stream>>>(vtmp, vt);
  k_stats<<<1024, 256, 0, stream>>>(qg, kg, ml);
  k_attn<<<512, 512, 0, stream>>>(qg, kg, vt, ml, mixg, lnhg, lnhb, dout + 1024, oh);
  k_epi<<<128, 512, 0, stream>>>(oh, woutT, bo, logv, lob, dout);
}